// Round 1
// baseline (5564.303 us; speedup 1.0000x reference)
//
#include <hip/hip_runtime.h>
#include <hip/hip_bf16.h>

// GCN forward: 2x GCNConv(128->128) + ELU + global mean pool + FC(128->1)
// Strategy: build dst-CSR per call (no atomics on feature path), gather-based
// aggregation (1 wave per node, float2 per lane), register-resident-W matmul.

#define NODES_PER_BLOCK 4   // waves per block in agg kernels

__global__ void init_kernel(float* __restrict__ deg, int* __restrict__ cnt,
                            float* __restrict__ gsum, int* __restrict__ gcnt, int n) {
    int i = blockIdx.x * blockDim.x + threadIdx.x;
    if (i < n) { deg[i] = 1.0f; cnt[i] = 0; }   // deg starts at 1.0 (self-loop weight)
    if (i < 64) { gsum[i] = 0.0f; gcnt[i] = 0; }
}

__global__ void edge_pass1(const int* __restrict__ dst, const float* __restrict__ ew,
                           float* __restrict__ deg, int* __restrict__ cnt, int E) {
    int e = blockIdx.x * blockDim.x + threadIdx.x;
    if (e >= E) return;
    int d = dst[e];
    atomicAdd(&deg[d], ew[e]);
    atomicAdd(&cnt[d], 1);
}

__global__ void compute_dinv(float* __restrict__ deg, int n) {
    int i = blockIdx.x * blockDim.x + threadIdx.x;
    if (i < n) deg[i] = rsqrtf(deg[i]);   // deg >= 1 always (self-loop)
}

// ---- 3-kernel exclusive scan of cnt -> rowptr ----
__global__ void scan_block(const int* __restrict__ cnt, int* __restrict__ rowptr,
                           int* __restrict__ partial, int n) {
    __shared__ int lds[256];
    int t = threadIdx.x;
    int i = blockIdx.x * 256 + t;
    int v = (i < n) ? cnt[i] : 0;
    lds[t] = v;
    __syncthreads();
    for (int off = 1; off < 256; off <<= 1) {
        int add = (t >= off) ? lds[t - off] : 0;
        __syncthreads();
        lds[t] += add;
        __syncthreads();
    }
    if (i < n) rowptr[i] = lds[t] - v;           // exclusive within block
    if (t == 255) partial[blockIdx.x] = lds[255]; // block total
}

__global__ void scan_partial(int* __restrict__ partial, int nb) {
    __shared__ int lds[1024];
    int t = threadIdx.x;
    int v = (t < nb) ? partial[t] : 0;
    lds[t] = v;
    __syncthreads();
    for (int off = 1; off < 1024; off <<= 1) {
        int add = (t >= off) ? lds[t - off] : 0;
        __syncthreads();
        lds[t] += add;
        __syncthreads();
    }
    if (t < nb) partial[t] = lds[t] - v;          // exclusive
}

__global__ void finalize_rowptr(int* __restrict__ rowptr, const int* __restrict__ partial,
                                int* __restrict__ cursor, int n, int e_total) {
    int i = blockIdx.x * 256 + threadIdx.x;
    if (i < n) {
        int v = rowptr[i] + partial[blockIdx.x];
        rowptr[i] = v;
        cursor[i] = v;
    }
    if (i == 0) rowptr[n] = e_total;
}

__global__ void edge_fill(const int* __restrict__ src, const int* __restrict__ dst,
                          const float* __restrict__ ew, const float* __restrict__ dinv,
                          int* __restrict__ cursor, int2* __restrict__ edges, int E) {
    int e = blockIdx.x * blockDim.x + threadIdx.x;
    if (e >= E) return;
    int s = src[e], d = dst[e];
    float w = dinv[s] * ew[e] * dinv[d];
    int pos = atomicAdd(&cursor[d], 1);
    edges[pos] = make_int2(s, __float_as_int(w));
}

// Y[n][col] = sum_k X[n][k] * W[k][col].  W column held in registers per lane.
// Each wave: 64 lanes = 64 cols (one 64-col half). Two waves cover a node stream.
__global__ __launch_bounds__(256, 2) void matmul_fc(const float* __restrict__ X,
                                                    const float* __restrict__ W,
                                                    float* __restrict__ Y, int n) {
    int wib = threadIdx.x >> 6, lane = threadIdx.x & 63;
    int wid = blockIdx.x * 4 + wib;
    int half = wid & 1;
    int col = (half << 6) | lane;
    float Wreg[128];
#pragma unroll
    for (int k = 0; k < 128; k++) Wreg[k] = W[k * 128 + col];
    int stride = (gridDim.x * 4) >> 1;
    for (int nn = wid >> 1; nn < n; nn += stride) {
        const float4* xr = (const float4*)(X + (size_t)nn * 128);
        float a0 = 0.f, a1 = 0.f;
#pragma unroll
        for (int k4 = 0; k4 < 32; k4 += 2) {
            float4 xa = xr[k4];
            float4 xb = xr[k4 + 1];
            a0 = fmaf(xa.x, Wreg[4 * k4 + 0], a0);
            a0 = fmaf(xa.y, Wreg[4 * k4 + 1], a0);
            a0 = fmaf(xa.z, Wreg[4 * k4 + 2], a0);
            a0 = fmaf(xa.w, Wreg[4 * k4 + 3], a0);
            a1 = fmaf(xb.x, Wreg[4 * k4 + 4], a1);
            a1 = fmaf(xb.y, Wreg[4 * k4 + 5], a1);
            a1 = fmaf(xb.z, Wreg[4 * k4 + 6], a1);
            a1 = fmaf(xb.w, Wreg[4 * k4 + 7], a1);
        }
        Y[(size_t)nn * 128 + col] = a0 + a1;
    }
}

// Aggregation layer 1: out = ELU( dinv[n]^2*H[n] + sum_e w_e*H[src_e] + b1 )
__global__ __launch_bounds__(256) void agg_elu(const float* __restrict__ H,
                                               const int2* __restrict__ edges,
                                               const int* __restrict__ rowptr,
                                               const float* __restrict__ dinv,
                                               const float* __restrict__ bias,
                                               float* __restrict__ out, int n) {
    int w = threadIdx.x >> 6, lane = threadIdx.x & 63;
    int node = blockIdx.x * NODES_PER_BLOCK + w;
    if (node >= n) return;
    const float2* Hf2 = (const float2*)H;
    float di = dinv[node];
    float sw = di * di;
    float2 acc = Hf2[(size_t)node * 64 + lane];
    acc.x *= sw; acc.y *= sw;
    int beg = rowptr[node], end = rowptr[node + 1];
    for (int base = beg; base < end; base += 64) {
        int cnt = end - base; if (cnt > 64) cnt = 64;
        int2 ed = make_int2(0, 0);
        if (lane < cnt) ed = edges[base + lane];
        int es = ed.x;
        float ef = __int_as_float(ed.y);
#pragma unroll 4
        for (int j = 0; j < cnt; j++) {
            int s = __shfl(es, j);
            float wj = __shfl(ef, j);
            float2 hv = Hf2[(size_t)s * 64 + lane];
            acc.x = fmaf(wj, hv.x, acc.x);
            acc.y = fmaf(wj, hv.y, acc.y);
        }
    }
    float ox = acc.x + bias[2 * lane];
    float oy = acc.y + bias[2 * lane + 1];
    ox = ox > 0.f ? ox : expm1f(ox);
    oy = oy > 0.f ? oy : expm1f(oy);
    ((float2*)out)[(size_t)node * 64 + lane] = make_float2(ox, oy);
}

// Aggregation layer 2 fused with pooling: row = dinv^2*H[n] + sum w*H[s] + b2;
// s_n = row . Wfc ; atomicAdd into per-graph sum + count.
__global__ __launch_bounds__(256) void agg_pool(const float* __restrict__ H,
                                                const int2* __restrict__ edges,
                                                const int* __restrict__ rowptr,
                                                const float* __restrict__ dinv,
                                                const float* __restrict__ bias,
                                                const float* __restrict__ wfc,
                                                const int* __restrict__ batch,
                                                float* __restrict__ gsum,
                                                int* __restrict__ gcnt, int n) {
    int w = threadIdx.x >> 6, lane = threadIdx.x & 63;
    int node = blockIdx.x * NODES_PER_BLOCK + w;
    if (node >= n) return;
    const float2* Hf2 = (const float2*)H;
    float di = dinv[node];
    float sw = di * di;
    float2 acc = Hf2[(size_t)node * 64 + lane];
    acc.x *= sw; acc.y *= sw;
    int beg = rowptr[node], end = rowptr[node + 1];
    for (int base = beg; base < end; base += 64) {
        int cnt = end - base; if (cnt > 64) cnt = 64;
        int2 ed = make_int2(0, 0);
        if (lane < cnt) ed = edges[base + lane];
        int es = ed.x;
        float ef = __int_as_float(ed.y);
#pragma unroll 4
        for (int j = 0; j < cnt; j++) {
            int s = __shfl(es, j);
            float wj = __shfl(ef, j);
            float2 hv = Hf2[(size_t)s * 64 + lane];
            acc.x = fmaf(wj, hv.x, acc.x);
            acc.y = fmaf(wj, hv.y, acc.y);
        }
    }
    float px = acc.x + bias[2 * lane];
    float py = acc.y + bias[2 * lane + 1];
    float partial = px * wfc[2 * lane] + py * wfc[2 * lane + 1];
#pragma unroll
    for (int off = 32; off; off >>= 1) partial += __shfl_xor(partial, off);
    if (lane == 0) {
        int g = batch[node];
        atomicAdd(&gsum[g], partial);
        atomicAdd(&gcnt[g], 1);
    }
}

__global__ void finalize_out(const float* __restrict__ gsum, const int* __restrict__ gcnt,
                             const float* __restrict__ bfc, float* __restrict__ out) {
    int g = threadIdx.x;
    if (g < 64) {
        float c = (float)gcnt[g];
        out[g] = gsum[g] / fmaxf(c, 1.0f) + bfc[0];
    }
}

extern "C" void kernel_launch(void* const* d_in, const int* in_sizes, int n_in,
                              void* d_out, int out_size, void* d_ws, size_t ws_size,
                              hipStream_t stream) {
    const int N = in_sizes[0] / 128;       // 200000
    const int E = in_sizes[2];             // 6400000

    const float* x     = (const float*)d_in[0];
    const int*   ei    = (const int*)d_in[1];
    const int*   src   = ei;
    const int*   dst   = ei + E;
    const float* ew    = (const float*)d_in[2];
    const int*   batch = (const int*)d_in[3];
    const float* W1    = (const float*)d_in[4];
    const float* b1    = (const float*)d_in[5];
    const float* W2    = (const float*)d_in[6];
    const float* b2    = (const float*)d_in[7];
    const float* Wfc   = (const float*)d_in[8];
    const float* bfc   = (const float*)d_in[9];
    float* out = (float*)d_out;

    // workspace carve (256B aligned)
    char* base = (char*)d_ws;
    size_t off = 0;
    auto carve = [&](size_t bytes) -> void* {
        void* r = base + off;
        off = (off + bytes + 255) & ~(size_t)255;
        return r;
    };
    float* hA      = (float*)carve((size_t)N * 128 * 4);
    float* hB      = (float*)carve((size_t)N * 128 * 4);
    int2*  edges   = (int2*) carve((size_t)E * 8);
    float* deg     = (float*)carve((size_t)N * 4);     // becomes dinv in place
    int*   rowptr  = (int*)  carve((size_t)(N + 1) * 4);
    int*   cursor  = (int*)  carve((size_t)N * 4);     // counts, then fill cursors
    int*   partial = (int*)  carve(1024 * 4);
    float* gsum    = (float*)carve(64 * 4);
    int*   gcnt    = (int*)  carve(64 * 4);

    const int NB = (N + 255) / 256;        // 782 scan blocks (<=1024)
    const int EB = (E + 255) / 256;
    const int AGGB = (N + NODES_PER_BLOCK - 1) / NODES_PER_BLOCK;

    hipLaunchKernelGGL(init_kernel, dim3(NB), dim3(256), 0, stream, deg, cursor, gsum, gcnt, N);
    hipLaunchKernelGGL(edge_pass1, dim3(EB), dim3(256), 0, stream, dst, ew, deg, cursor, E);
    hipLaunchKernelGGL(compute_dinv, dim3(NB), dim3(256), 0, stream, deg, N);
    hipLaunchKernelGGL(scan_block, dim3(NB), dim3(256), 0, stream, cursor, rowptr, partial, N);
    hipLaunchKernelGGL(scan_partial, dim3(1), dim3(1024), 0, stream, partial, NB);
    hipLaunchKernelGGL(finalize_rowptr, dim3(NB), dim3(256), 0, stream, rowptr, partial, cursor, N, E);
    hipLaunchKernelGGL(edge_fill, dim3(EB), dim3(256), 0, stream, src, dst, ew, deg, cursor, edges, E);
    // layer 1
    hipLaunchKernelGGL(matmul_fc, dim3(2048), dim3(256), 0, stream, x, W1, hA, N);
    hipLaunchKernelGGL(agg_elu, dim3(AGGB), dim3(256), 0, stream, hA, edges, rowptr, deg, b1, hB, N);
    // layer 2
    hipLaunchKernelGGL(matmul_fc, dim3(2048), dim3(256), 0, stream, hB, W2, hA, N);
    hipLaunchKernelGGL(agg_pool, dim3(AGGB), dim3(256), 0, stream, hA, edges, rowptr, deg, b2, Wfc, batch, gsum, gcnt, N);
    // pool finalize
    hipLaunchKernelGGL(finalize_out, dim3(1), dim3(64), 0, stream, gsum, gcnt, bfc, out);
}

// Round 2
// 5369.143 us; speedup vs baseline: 1.0363x; 1.0363x over previous
//
#include <hip/hip_runtime.h>
#include <hip/hip_bf16.h>

// GCN forward: 2x GCNConv(128->128) + ELU + global mean pool + FC(128->1)
// R1: 8-deep MLP in the aggregation gather loop (was the 2x2156us bottleneck,
// latency-bound at VALUBusy 4.5%). 4 rotating accumulators, padded chunks
// (src=0,w=0) remove the scalar tail.

#define NODES_PER_BLOCK 4   // waves per block in agg kernels

__global__ void init_kernel(float* __restrict__ deg, int* __restrict__ cnt,
                            float* __restrict__ gsum, int* __restrict__ gcnt, int n) {
    int i = blockIdx.x * blockDim.x + threadIdx.x;
    if (i < n) { deg[i] = 1.0f; cnt[i] = 0; }   // deg starts at 1.0 (self-loop weight)
    if (i < 64) { gsum[i] = 0.0f; gcnt[i] = 0; }
}

__global__ void edge_pass1(const int* __restrict__ dst, const float* __restrict__ ew,
                           float* __restrict__ deg, int* __restrict__ cnt, int E) {
    int e = blockIdx.x * blockDim.x + threadIdx.x;
    if (e >= E) return;
    int d = dst[e];
    atomicAdd(&deg[d], ew[e]);
    atomicAdd(&cnt[d], 1);
}

__global__ void compute_dinv(float* __restrict__ deg, int n) {
    int i = blockIdx.x * blockDim.x + threadIdx.x;
    if (i < n) deg[i] = rsqrtf(deg[i]);   // deg >= 1 always (self-loop)
}

// ---- 3-kernel exclusive scan of cnt -> rowptr ----
__global__ void scan_block(const int* __restrict__ cnt, int* __restrict__ rowptr,
                           int* __restrict__ partial, int n) {
    __shared__ int lds[256];
    int t = threadIdx.x;
    int i = blockIdx.x * 256 + t;
    int v = (i < n) ? cnt[i] : 0;
    lds[t] = v;
    __syncthreads();
    for (int off = 1; off < 256; off <<= 1) {
        int add = (t >= off) ? lds[t - off] : 0;
        __syncthreads();
        lds[t] += add;
        __syncthreads();
    }
    if (i < n) rowptr[i] = lds[t] - v;           // exclusive within block
    if (t == 255) partial[blockIdx.x] = lds[255]; // block total
}

__global__ void scan_partial(int* __restrict__ partial, int nb) {
    __shared__ int lds[1024];
    int t = threadIdx.x;
    int v = (t < nb) ? partial[t] : 0;
    lds[t] = v;
    __syncthreads();
    for (int off = 1; off < 1024; off <<= 1) {
        int add = (t >= off) ? lds[t - off] : 0;
        __syncthreads();
        lds[t] += add;
        __syncthreads();
    }
    if (t < nb) partial[t] = lds[t] - v;          // exclusive
}

__global__ void finalize_rowptr(int* __restrict__ rowptr, const int* __restrict__ partial,
                                int* __restrict__ cursor, int n, int e_total) {
    int i = blockIdx.x * 256 + threadIdx.x;
    if (i < n) {
        int v = rowptr[i] + partial[blockIdx.x];
        rowptr[i] = v;
        cursor[i] = v;
    }
    if (i == 0) rowptr[n] = e_total;
}

__global__ void edge_fill(const int* __restrict__ src, const int* __restrict__ dst,
                          const float* __restrict__ ew, const float* __restrict__ dinv,
                          int* __restrict__ cursor, int2* __restrict__ edges, int E) {
    int e = blockIdx.x * blockDim.x + threadIdx.x;
    if (e >= E) return;
    int s = src[e], d = dst[e];
    float w = dinv[s] * ew[e] * dinv[d];
    int pos = atomicAdd(&cursor[d], 1);
    edges[pos] = make_int2(s, __float_as_int(w));
}

// Y[n][col] = sum_k X[n][k] * W[k][col].  W column held in registers per lane.
__global__ __launch_bounds__(256, 2) void matmul_fc(const float* __restrict__ X,
                                                    const float* __restrict__ W,
                                                    float* __restrict__ Y, int n) {
    int wib = threadIdx.x >> 6, lane = threadIdx.x & 63;
    int wid = blockIdx.x * 4 + wib;
    int half = wid & 1;
    int col = (half << 6) | lane;
    float Wreg[128];
#pragma unroll
    for (int k = 0; k < 128; k++) Wreg[k] = W[k * 128 + col];
    int stride = (gridDim.x * 4) >> 1;
    for (int nn = wid >> 1; nn < n; nn += stride) {
        const float4* xr = (const float4*)(X + (size_t)nn * 128);
        float a0 = 0.f, a1 = 0.f;
#pragma unroll
        for (int k4 = 0; k4 < 32; k4 += 2) {
            float4 xa = xr[k4];
            float4 xb = xr[k4 + 1];
            a0 = fmaf(xa.x, Wreg[4 * k4 + 0], a0);
            a0 = fmaf(xa.y, Wreg[4 * k4 + 1], a0);
            a0 = fmaf(xa.z, Wreg[4 * k4 + 2], a0);
            a0 = fmaf(xa.w, Wreg[4 * k4 + 3], a0);
            a1 = fmaf(xb.x, Wreg[4 * k4 + 4], a1);
            a1 = fmaf(xb.y, Wreg[4 * k4 + 5], a1);
            a1 = fmaf(xb.z, Wreg[4 * k4 + 6], a1);
            a1 = fmaf(xb.w, Wreg[4 * k4 + 7], a1);
        }
        Y[(size_t)nn * 128 + col] = a0 + a1;
    }
}

// 8-deep MLP gather over one node's CSR edge range. Each lane owns 2 features.
// Returns accumulated float2 (init = self-loop contribution).
__device__ __forceinline__ float2 gather_row(const float2* __restrict__ Hf2,
                                             const int2* __restrict__ edges,
                                             int beg, int end, int lane, float2 init) {
    float2 a0 = init;
    float2 a1 = make_float2(0.f, 0.f);
    float2 a2 = make_float2(0.f, 0.f);
    float2 a3 = make_float2(0.f, 0.f);
    for (int base = beg; base < end; base += 64) {
        int cnt = end - base; if (cnt > 64) cnt = 64;
        int2 ed = make_int2(0, 0);               // pad: src=0, w=0.0f
        if (lane < cnt) ed = edges[base + lane];
        int es = ed.x;
        float ef = __int_as_float(ed.y);
        int cnt8 = (cnt + 7) & ~7;               // padded lanes are harmless
        for (int j = 0; j < cnt8; j += 8) {
            int s0 = __shfl(es, j + 0), s1 = __shfl(es, j + 1);
            int s2 = __shfl(es, j + 2), s3 = __shfl(es, j + 3);
            int s4 = __shfl(es, j + 4), s5 = __shfl(es, j + 5);
            int s6 = __shfl(es, j + 6), s7 = __shfl(es, j + 7);
            float w0 = __shfl(ef, j + 0), w1 = __shfl(ef, j + 1);
            float w2 = __shfl(ef, j + 2), w3 = __shfl(ef, j + 3);
            float w4 = __shfl(ef, j + 4), w5 = __shfl(ef, j + 5);
            float w6 = __shfl(ef, j + 6), w7 = __shfl(ef, j + 7);
            float2 h0 = Hf2[(size_t)s0 * 64 + lane];
            float2 h1 = Hf2[(size_t)s1 * 64 + lane];
            float2 h2 = Hf2[(size_t)s2 * 64 + lane];
            float2 h3 = Hf2[(size_t)s3 * 64 + lane];
            float2 h4 = Hf2[(size_t)s4 * 64 + lane];
            float2 h5 = Hf2[(size_t)s5 * 64 + lane];
            float2 h6 = Hf2[(size_t)s6 * 64 + lane];
            float2 h7 = Hf2[(size_t)s7 * 64 + lane];
            a0.x = fmaf(w0, h0.x, a0.x); a0.y = fmaf(w0, h0.y, a0.y);
            a1.x = fmaf(w1, h1.x, a1.x); a1.y = fmaf(w1, h1.y, a1.y);
            a2.x = fmaf(w2, h2.x, a2.x); a2.y = fmaf(w2, h2.y, a2.y);
            a3.x = fmaf(w3, h3.x, a3.x); a3.y = fmaf(w3, h3.y, a3.y);
            a0.x = fmaf(w4, h4.x, a0.x); a0.y = fmaf(w4, h4.y, a0.y);
            a1.x = fmaf(w5, h5.x, a1.x); a1.y = fmaf(w5, h5.y, a1.y);
            a2.x = fmaf(w6, h6.x, a2.x); a2.y = fmaf(w6, h6.y, a2.y);
            a3.x = fmaf(w7, h7.x, a3.x); a3.y = fmaf(w7, h7.y, a3.y);
        }
    }
    a0.x += a1.x + a2.x + a3.x;
    a0.y += a1.y + a2.y + a3.y;
    return a0;
}

// Aggregation layer 1: out = ELU( dinv[n]^2*H[n] + sum_e w_e*H[src_e] + b1 )
__global__ __launch_bounds__(256) void agg_elu(const float* __restrict__ H,
                                               const int2* __restrict__ edges,
                                               const int* __restrict__ rowptr,
                                               const float* __restrict__ dinv,
                                               const float* __restrict__ bias,
                                               float* __restrict__ out, int n) {
    int w = threadIdx.x >> 6, lane = threadIdx.x & 63;
    int node = blockIdx.x * NODES_PER_BLOCK + w;
    if (node >= n) return;
    const float2* Hf2 = (const float2*)H;
    float di = dinv[node];
    float sw = di * di;
    float2 own = Hf2[(size_t)node * 64 + lane];
    float2 acc = gather_row(Hf2, edges, rowptr[node], rowptr[node + 1], lane,
                            make_float2(own.x * sw, own.y * sw));
    float ox = acc.x + bias[2 * lane];
    float oy = acc.y + bias[2 * lane + 1];
    ox = ox > 0.f ? ox : expm1f(ox);
    oy = oy > 0.f ? oy : expm1f(oy);
    ((float2*)out)[(size_t)node * 64 + lane] = make_float2(ox, oy);
}

// Aggregation layer 2 fused with pooling: row = dinv^2*H[n] + sum w*H[s] + b2;
// s_n = row . Wfc ; atomicAdd into per-graph sum + count.
__global__ __launch_bounds__(256) void agg_pool(const float* __restrict__ H,
                                                const int2* __restrict__ edges,
                                                const int* __restrict__ rowptr,
                                                const float* __restrict__ dinv,
                                                const float* __restrict__ bias,
                                                const float* __restrict__ wfc,
                                                const int* __restrict__ batch,
                                                float* __restrict__ gsum,
                                                int* __restrict__ gcnt, int n) {
    int w = threadIdx.x >> 6, lane = threadIdx.x & 63;
    int node = blockIdx.x * NODES_PER_BLOCK + w;
    if (node >= n) return;
    const float2* Hf2 = (const float2*)H;
    float di = dinv[node];
    float sw = di * di;
    float2 own = Hf2[(size_t)node * 64 + lane];
    float2 acc = gather_row(Hf2, edges, rowptr[node], rowptr[node + 1], lane,
                            make_float2(own.x * sw, own.y * sw));
    float px = acc.x + bias[2 * lane];
    float py = acc.y + bias[2 * lane + 1];
    float partial = px * wfc[2 * lane] + py * wfc[2 * lane + 1];
#pragma unroll
    for (int off = 32; off; off >>= 1) partial += __shfl_xor(partial, off);
    if (lane == 0) {
        int g = batch[node];
        atomicAdd(&gsum[g], partial);
        atomicAdd(&gcnt[g], 1);
    }
}

__global__ void finalize_out(const float* __restrict__ gsum, const int* __restrict__ gcnt,
                             const float* __restrict__ bfc, float* __restrict__ out) {
    int g = threadIdx.x;
    if (g < 64) {
        float c = (float)gcnt[g];
        out[g] = gsum[g] / fmaxf(c, 1.0f) + bfc[0];
    }
}

extern "C" void kernel_launch(void* const* d_in, const int* in_sizes, int n_in,
                              void* d_out, int out_size, void* d_ws, size_t ws_size,
                              hipStream_t stream) {
    const int N = in_sizes[0] / 128;       // 200000
    const int E = in_sizes[2];             // 6400000

    const float* x     = (const float*)d_in[0];
    const int*   ei    = (const int*)d_in[1];
    const int*   src   = ei;
    const int*   dst   = ei + E;
    const float* ew    = (const float*)d_in[2];
    const int*   batch = (const int*)d_in[3];
    const float* W1    = (const float*)d_in[4];
    const float* b1    = (const float*)d_in[5];
    const float* W2    = (const float*)d_in[6];
    const float* b2    = (const float*)d_in[7];
    const float* Wfc   = (const float*)d_in[8];
    const float* bfc   = (const float*)d_in[9];
    float* out = (float*)d_out;

    // workspace carve (256B aligned)
    char* base = (char*)d_ws;
    size_t off = 0;
    auto carve = [&](size_t bytes) -> void* {
        void* r = base + off;
        off = (off + bytes + 255) & ~(size_t)255;
        return r;
    };
    float* hA      = (float*)carve((size_t)N * 128 * 4);
    float* hB      = (float*)carve((size_t)N * 128 * 4);
    int2*  edges   = (int2*) carve((size_t)E * 8);
    float* deg     = (float*)carve((size_t)N * 4);     // becomes dinv in place
    int*   rowptr  = (int*)  carve((size_t)(N + 1) * 4);
    int*   cursor  = (int*)  carve((size_t)N * 4);     // counts, then fill cursors
    int*   partial = (int*)  carve(1024 * 4);
    float* gsum    = (float*)carve(64 * 4);
    int*   gcnt    = (int*)  carve(64 * 4);

    const int NB = (N + 255) / 256;        // 782 scan blocks (<=1024)
    const int EB = (E + 255) / 256;
    const int AGGB = (N + NODES_PER_BLOCK - 1) / NODES_PER_BLOCK;

    hipLaunchKernelGGL(init_kernel, dim3(NB), dim3(256), 0, stream, deg, cursor, gsum, gcnt, N);
    hipLaunchKernelGGL(edge_pass1, dim3(EB), dim3(256), 0, stream, dst, ew, deg, cursor, E);
    hipLaunchKernelGGL(compute_dinv, dim3(NB), dim3(256), 0, stream, deg, N);
    hipLaunchKernelGGL(scan_block, dim3(NB), dim3(256), 0, stream, cursor, rowptr, partial, N);
    hipLaunchKernelGGL(scan_partial, dim3(1), dim3(1024), 0, stream, partial, NB);
    hipLaunchKernelGGL(finalize_rowptr, dim3(NB), dim3(256), 0, stream, rowptr, partial, cursor, N, E);
    hipLaunchKernelGGL(edge_fill, dim3(EB), dim3(256), 0, stream, src, dst, ew, deg, cursor, edges, E);
    // layer 1
    hipLaunchKernelGGL(matmul_fc, dim3(2048), dim3(256), 0, stream, x, W1, hA, N);
    hipLaunchKernelGGL(agg_elu, dim3(AGGB), dim3(256), 0, stream, hA, edges, rowptr, deg, b1, hB, N);
    // layer 2
    hipLaunchKernelGGL(matmul_fc, dim3(2048), dim3(256), 0, stream, hB, W2, hA, N);
    hipLaunchKernelGGL(agg_pool, dim3(AGGB), dim3(256), 0, stream, hA, edges, rowptr, deg, b2, Wfc, batch, gsum, gcnt, N);
    // pool finalize
    hipLaunchKernelGGL(finalize_out, dim3(1), dim3(64), 0, stream, gsum, gcnt, bfc, out);
}